// Round 9
// baseline (173.371 us; speedup 1.0000x reference)
//
#include <hip/hip_runtime.h>

#define BB 2048
#define AA 96
#define NIN 128
#define NHID 64
#define MI 2                 // 16-atom tiles per wave; 1536 blocks = 6/CU = 24 waves/CU

typedef __attribute__((ext_vector_type(8))) short bf16x8;
typedef __attribute__((ext_vector_type(4))) float f32x4;

static __device__ __forceinline__ unsigned f2bf(float x) {
    unsigned u = __builtin_bit_cast(unsigned, x);
    return (u + 0x7FFFu + ((u >> 16) & 1u)) >> 16;
}
static __device__ __forceinline__ unsigned cvt_pk(float a, float b) {
    return f2bf(a) | (f2bf(b) << 16);
}

// R2-R8 lesson: compiler pins ~64 VGPR/wave. Live set here: q[8](32)+acc(16)
// +fa(4)+addr ~= 58 -> fits, no spill, but all 8 tile loads in flight (R8 had
// only 2 -> 4 serial stalls/tile). Occupancy raised 16->24 waves/CU via MI=2.
// Frag image in LDS [(s*4+t)*64+lane]*16B: ds_read_b128 base+lane*16,
// conflict-free. Layouts validated R6/R8 (absmax 0.0625).
__global__ __launch_bounds__(256) void atomwise_kernel(
    const float* __restrict__ rep,
    const int*   __restrict__ zs,
    const float* __restrict__ mask,
    const float* __restrict__ w1,    // [NIN][NHID] fp32
    const float* __restrict__ b1,
    const float* __restrict__ w2,
    const float* __restrict__ b2,
    const float* __restrict__ aref,
    const float* __restrict__ mean,
    const float* __restrict__ stddev,
    float* __restrict__ out)
{
    __shared__ bf16x8 w1f[1024];          // 16 KB frag image
    __shared__ float  b1s[NHID], w2s[NHID];

    const int tid  = threadIdx.x;
    const int lane = tid & 63;
    const int wv   = tid >> 6;
    const int nl   = lane & 15;
    const int quad = lane >> 4;

    // ---- stage W1 -> frag image: coalesced float4 reads, u16 scatter to LDS
    {
        unsigned short* w1h = (unsigned short*)w1f;
        const float4* w14 = (const float4*)w1;
        #pragma unroll
        for (int i = 0; i < 8; ++i) {
            const int idx = tid + i * 256;        // float4 idx 0..2047
            const float4 v = w14[idx];
            const int k  = idx >> 4;              // row of W1
            const int n0 = (idx & 15) * 4;        // first of 4 consecutive cols
            const int s = k >> 5, qd = (k >> 3) & 3, jp = (k & 7) >> 1, hf = k & 1;
            const int t = n0 >> 4;
            // u16 index: frag*8 + jp*2 + hf ; frag = (s*4+t)*64 + qd*16 + nl
            const int base = ((s * 4 + t) * 64 + qd * 16 + (n0 & 15)) * 8 + jp * 2 + hf;
            w1h[base     ] = (unsigned short)f2bf(v.x);
            w1h[base +  8] = (unsigned short)f2bf(v.y);
            w1h[base + 16] = (unsigned short)f2bf(v.z);
            w1h[base + 24] = (unsigned short)f2bf(v.w);
        }
        if (tid < NHID)            b1s[tid] = b1[tid];
        else if (tid < 2 * NHID)   w2s[tid - NHID] = w2[tid - NHID];
    }
    __syncthreads();

    const float sdv  = stddev[0];
    const float cadd = fmaf(b2[0], sdv, mean[0]);
    const float LOG2E = 1.4426950408889634f;
    const float LN2   = 0.6931471805599453f;

    const int wid = blockIdx.x * 4 + wv;

    #pragma unroll 1
    for (int mt = 0; mt < MI; ++mt) {
        const int atom0 = (wid * MI + mt) * 16;
        const float* rowp = rep + (size_t)(atom0 + nl) * NIN + quad * 8;

        // all 8 tile loads issued before any use -> one latency exposure/tile
        float4 q[8];
        #pragma unroll
        for (int s = 0; s < 4; ++s) {
            q[2 * s]     = *(const float4*)(rowp + s * 32);
            q[2 * s + 1] = *(const float4*)(rowp + s * 32 + 4);
        }

        f32x4 acc[4];
        #pragma unroll
        for (int t = 0; t < 4; ++t) acc[t] = (f32x4){0.f, 0.f, 0.f, 0.f};

        #pragma unroll
        for (int s = 0; s < 4; ++s) {
            union { bf16x8 v; unsigned u[4]; } fa;
            fa.u[0] = cvt_pk(q[2 * s].x,     q[2 * s].y);
            fa.u[1] = cvt_pk(q[2 * s].z,     q[2 * s].w);
            fa.u[2] = cvt_pk(q[2 * s + 1].x, q[2 * s + 1].y);
            fa.u[3] = cvt_pk(q[2 * s + 1].z, q[2 * s + 1].w);
            const bf16x8* fr = &w1f[s * 256 + lane];
            #pragma unroll
            for (int t = 0; t < 4; ++t)
                acc[t] = __builtin_amdgcn_mfma_f32_16x16x32_bf16(fa.v, fr[t * 64], acc[t], 0, 0, 0);
        }

        // epilogue: softplus, dot w2, 16-lane reduce, 1 atomic/tile
        float v[4];
        #pragma unroll
        for (int r = 0; r < 4; ++r) {
            float p = 0.f;
            #pragma unroll
            for (int t = 0; t < 4; ++t) {
                float x  = acc[t][r] + b1s[t * 16 + nl];
                float ax = fabsf(x);
                float em = exp2f(-ax * LOG2E);
                float sp = fmaxf(x, 0.f) + log2f(1.f + em) * LN2;
                p = fmaf(sp - LN2, w2s[t * 16 + nl], p);
            }
            p += __shfl_xor(p, 1); p += __shfl_xor(p, 2);
            p += __shfl_xor(p, 4); p += __shfl_xor(p, 8);
            v[r] = p;
        }
        if (nl == 0) {                          // lanes 0,16,32,48
            float ssum = 0.f;
            #pragma unroll
            for (int r = 0; r < 4; ++r) {
                const int ag = atom0 + quad * 4 + r;
                const float yi = fmaf(v[r], sdv, cadd) + aref[zs[ag]];
                ssum += mask[ag] * yi;
            }
            ssum += __shfl_xor(ssum, 16);
            ssum += __shfl_xor(ssum, 32);
            if (lane == 0) atomicAdd(out + atom0 / AA, ssum);  // 16 | 96
        }
    }
}

extern "C" void kernel_launch(void* const* d_in, const int* in_sizes, int n_in,
                              void* d_out, int out_size, void* d_ws, size_t ws_size,
                              hipStream_t stream) {
    const float* rep    = (const float*)d_in[0];
    const int*   zs     = (const int*)  d_in[1];
    const float* mask   = (const float*)d_in[2];
    const float* w1     = (const float*)d_in[3];
    const float* b1     = (const float*)d_in[4];
    const float* w2     = (const float*)d_in[5];
    const float* b2     = (const float*)d_in[6];
    const float* aref   = (const float*)d_in[7];
    const float* mean   = (const float*)d_in[8];
    const float* stddev = (const float*)d_in[9];
    float* out = (float*)d_out;

    (void)hipMemsetAsync(out, 0, (size_t)out_size * sizeof(float), stream);

    const int atoms  = BB * AA;                  // 196608
    const int blocks = atoms / (4 * 16 * MI);    // 1536 -> 6 blocks/CU, one round
    atomwise_kernel<<<dim3(blocks), dim3(256), 0, stream>>>(
        rep, zs, mask, w1, b1, w2, b2, aref, mean, stddev, out);
}

// Round 10
// 163.351 us; speedup vs baseline: 1.0613x; 1.0613x over previous
//
#include <hip/hip_runtime.h>
#include <hip/hip_bf16.h>

#define BB 2048
#define AA 96
#define NIN 128
#define NHID 64

typedef __attribute__((ext_vector_type(8))) short bf16x8;
typedef __attribute__((ext_vector_type(4))) float f32x4;

// manual RNE for prep (tiny, once); main kernel uses HW v_cvt_pk
static __device__ __forceinline__ unsigned short f2bf(float x) {
    unsigned u = __builtin_bit_cast(unsigned, x);
    return (unsigned short)((u + 0x7FFFu + ((u >> 16) & 1u)) >> 16);
}
static __device__ __forceinline__ unsigned cvt_pk_hw(float a, float b) {
    __hip_bfloat162 h = __float22bfloat162_rn(make_float2(a, b));
    unsigned u; __builtin_memcpy(&u, &h, 4);   // memcpy: no triviality requirement
    return u;
}

// ws image (16896 B):
//   [0,16384)     bf16 frag image, 1024 frags x 16B, fid = (s*4+t)*64 + lane
//                 lane's elems: k = s*32 + (lane>>4)*8 + j, n = t*16 + (lane&15)
//                 (byte-identical to the R8-validated LDS layout)
//   [16384,16640) b1 f32[64]
//   [16640,16896) w2 f32[64]
__global__ void prep_kernel(const float* __restrict__ w1,
                            const float* __restrict__ b1,
                            const float* __restrict__ w2,
                            unsigned char* __restrict__ ws) {
    const int gid = blockIdx.x * 256 + threadIdx.x;
    if (gid < 1024) {
        const int lane = gid & 63, st = gid >> 6;
        const int s = st >> 2, t = st & 3;
        const int k0 = s * 32 + (lane >> 4) * 8;
        const int n  = t * 16 + (lane & 15);
        unsigned short o[8];
        #pragma unroll
        for (int j = 0; j < 8; ++j) o[j] = f2bf(w1[(k0 + j) * NHID + n]);
        uint4 v; __builtin_memcpy(&v, o, 16);
        ((uint4*)ws)[gid] = v;
    } else if (gid < 1088) {
        ((float*)(ws + 16384))[gid - 1024] = b1[gid - 1024];
    } else if (gid < 1152) {
        ((float*)(ws + 16640))[gid - 1088] = w2[gid - 1088];
    }
}

// wave = one 16-atom x 64-hid tile (mfma_f32_16x16x32_bf16). 3072 blocks.
// Staging = linear uint4 copy of the prebuilt image (no cvt, no scatter, no
// conflicts); one barrier drains staging + all 8 rep loads: single latency
// exposure per wave, hidden by 8 waves/SIMD (64-VGPR envelope, R2-R9 lesson).
// Layouts validated R6/R8 (absmax 0.0625): A m=nl,k=quad*8+j; C atom=quad*4+r, hid=nl.
__global__ __launch_bounds__(256) void atomwise_kernel(
    const float* __restrict__ rep,
    const int*   __restrict__ zs,
    const float* __restrict__ mask,
    const unsigned char* __restrict__ ws,   // frag image + b1 + w2
    const float* __restrict__ b2,
    const float* __restrict__ aref,
    const float* __restrict__ mean,
    const float* __restrict__ stddev,
    float* __restrict__ out)
{
    __shared__ unsigned char smem[16896];

    const int tid  = threadIdx.x;
    const int lane = tid & 63;
    const int wv   = tid >> 6;
    const int nl   = lane & 15;
    const int quad = lane >> 4;
    const int atom0 = (blockIdx.x * 4 + wv) * 16;

    // rep loads first (oldest in vm queue)
    const float* rowp = rep + (size_t)(atom0 + nl) * NIN + quad * 8;
    float4 q[8];
    #pragma unroll
    for (int s = 0; s < 4; ++s) {
        q[2 * s]     = *(const float4*)(rowp + s * 32);
        q[2 * s + 1] = *(const float4*)(rowp + s * 32 + 4);
    }

    // epilogue operands prefetched in parallel (R9 had a serial lane-0 chain)
    const int   ag    = atom0 + quad * 4 + (nl & 3);
    const float mq    = mask[ag];
    const float arefv = aref[zs[ag]];

    // stage image -> LDS: linear, coalesced, conflict-free ds_write_b128
    {
        const uint4* src = (const uint4*)ws;
        uint4*       dst = (uint4*)smem;
        #pragma unroll
        for (int i = 0; i < 4; ++i) dst[tid + i * 256] = src[tid + i * 256];
        if (tid < 32) dst[1024 + tid] = src[1024 + tid];
    }
    __syncthreads();

    const bf16x8* w1f = (const bf16x8*)smem;
    const float*  b1s = (const float*)(smem + 16384);
    const float*  w2s = (const float*)(smem + 16640);

    const float sdv  = stddev[0];
    const float cadd = fmaf(b2[0], sdv, mean[0]);
    const float LOG2E = 1.4426950408889634f;
    const float LN2   = 0.6931471805599453f;

    f32x4 acc[4];
    #pragma unroll
    for (int t = 0; t < 4; ++t) acc[t] = (f32x4){0.f, 0.f, 0.f, 0.f};

    #pragma unroll
    for (int s = 0; s < 4; ++s) {
        union { bf16x8 v; unsigned u[4]; } fa;
        fa.u[0] = cvt_pk_hw(q[2 * s].x,     q[2 * s].y);
        fa.u[1] = cvt_pk_hw(q[2 * s].z,     q[2 * s].w);
        fa.u[2] = cvt_pk_hw(q[2 * s + 1].x, q[2 * s + 1].y);
        fa.u[3] = cvt_pk_hw(q[2 * s + 1].z, q[2 * s + 1].w);
        const bf16x8* fr = &w1f[s * 256 + lane];
        #pragma unroll
        for (int t = 0; t < 4; ++t)
            acc[t] = __builtin_amdgcn_mfma_f32_16x16x32_bf16(fa.v, fr[t * 64], acc[t], 0, 0, 0);
    }

    // softplus + dot(w2) ; xor-reduce leaves per-quad sums in all 16 lanes
    float v[4];
    #pragma unroll
    for (int r = 0; r < 4; ++r) {
        float p = 0.f;
        #pragma unroll
        for (int t = 0; t < 4; ++t) {
            float x  = acc[t][r] + b1s[t * 16 + nl];
            float ax = fabsf(x);
            float em = exp2f(-ax * LOG2E);
            float sp = fmaxf(x, 0.f) + log2f(1.f + em) * LN2;
            p = fmaf(sp - LN2, w2s[t * 16 + nl], p);
        }
        p += __shfl_xor(p, 1); p += __shfl_xor(p, 2);
        p += __shfl_xor(p, 4); p += __shfl_xor(p, 8);
        v[r] = p;
    }

    // lanes nl<4 own atom quad*4+nl; select v[nl] without dynamic indexing
    const int rsel = nl & 3;
    float vr = v[0];
    vr = rsel == 1 ? v[1] : vr;
    vr = rsel == 2 ? v[2] : vr;
    vr = rsel == 3 ? v[3] : vr;
    float contrib = (nl < 4) ? mq * (fmaf(vr, sdv, cadd) + arefv) : 0.f;
    #pragma unroll
    for (int off = 32; off; off >>= 1) contrib += __shfl_xor(contrib, off);
    if (lane == 0) atomicAdd(out + atom0 / AA, contrib);   // 16 | 96: one molecule/tile
}

extern "C" void kernel_launch(void* const* d_in, const int* in_sizes, int n_in,
                              void* d_out, int out_size, void* d_ws, size_t ws_size,
                              hipStream_t stream) {
    const float* rep    = (const float*)d_in[0];
    const int*   zs     = (const int*)  d_in[1];
    const float* mask   = (const float*)d_in[2];
    const float* w1     = (const float*)d_in[3];
    const float* b1     = (const float*)d_in[4];
    const float* w2     = (const float*)d_in[5];
    const float* b2     = (const float*)d_in[6];
    const float* aref   = (const float*)d_in[7];
    const float* mean   = (const float*)d_in[8];
    const float* stddev = (const float*)d_in[9];
    float* out = (float*)d_out;
    unsigned char* ws = (unsigned char*)d_ws;

    (void)hipMemsetAsync(out, 0, (size_t)out_size * sizeof(float), stream);

    prep_kernel<<<dim3(5), dim3(256), 0, stream>>>(w1, b1, w2, ws);

    const int blocks = (BB * AA) / (4 * 16);     // 3072: wave = one 16-atom tile
    atomwise_kernel<<<dim3(blocks), dim3(256), 0, stream>>>(
        rep, zs, mask, ws, b2, aref, mean, stddev, out);
}